// Round 3
// baseline (533.306 us; speedup 1.0000x reference)
//
#include <hip/hip_runtime.h>
#include <hip/hip_bf16.h>

#define BB 64
#define SS 8192
#define DD 128

typedef __attribute__((ext_vector_type(8))) short bf16x8;
typedef __attribute__((ext_vector_type(4))) float f32x4;

__device__ __forceinline__ unsigned pk2(float x, float y) {
    // v_cvt_pk_bf16_f32 on gfx950 via HIP intrinsic (RNE)
    __hip_bfloat162 h = __float22bfloat162_rn(make_float2(x, y));
    union { __hip_bfloat162 h2; unsigned u; } c;
    c.h2 = h;
    return c.u;
}

__device__ __forceinline__ float tanh_fast(float x) {
    float e = __expf(2.f * x);
    return 1.f - 2.f / (e + 1.f);
}

// ---------------- K1: q = tanh(input @ W_dec^T + b_dec)
__global__ void qproj_kernel(const float* __restrict__ input,
                             const float* __restrict__ W_dec,
                             const float* __restrict__ b_dec,
                             float* __restrict__ q) {
    __shared__ float xin[DD];
    const int b = blockIdx.x, d = threadIdx.x;  // 128 threads
    xin[d] = input[b * DD + d];
    __syncthreads();
    const float4* wrow = (const float4*)(W_dec + (size_t)d * DD);
    float acc = 0.f;
#pragma unroll
    for (int k4 = 0; k4 < DD / 4; k4++) {
        float4 w = wrow[k4];
        float4 x = ((const float4*)xin)[k4];
        acc += w.x * x.x + w.y * x.y + w.z * x.z + w.w * x.w;
    }
    q[b * DD + d] = tanh_fast(acc + b_dec[d]);
}

// ---------------- K2: fused scores + online-softmax partials + weighted ctx sum
// Grid: 64 batches x 16 chunk-blocks; each block: 8 tiles of 64 rows.
// ctx staged dense global->VGPR (1KB/instr), packed bf16 into XOR-swizzled
// fragment-order LDS (conflict-free b128 reads). Weighted sum accumulated
// from the fp32 register tile with flash-style (M,T) rescaling.
__global__ __launch_bounds__(256, 3) void score_fused_kernel(
    const float* __restrict__ ctx,
    const float* __restrict__ W_enc,
    const float* __restrict__ b_enc,
    const float* __restrict__ q,
    float* __restrict__ scores,
    float* __restrict__ wcp,   // [1024][128] per-block weighted-ctx partials
    float* __restrict__ Mp,    // [1024]
    float* __restrict__ Tp) {  // [1024]
    __shared__ __align__(16) short Wl[2048 * 8];  // 32 KB, fragment-order W_enc
    __shared__ __align__(16) short Cl[64 * 128];  // 16 KB, swizzled ctx tile (bf16)
    __shared__ float sw[64];

    const int t = threadIdx.x;

    // ---- stage W_enc in MFMA B-fragment order (same layout as r2, new pack)
    const float4* W4 = (const float4*)W_enc;
    for (int c2 = t; c2 < 2048; c2 += 256) {
        int row = c2 >> 4, kc = c2 & 15;
        float4 f0 = W4[row * 32 + kc * 2];
        float4 f1 = W4[row * 32 + kc * 2 + 1];
        int nt = row >> 4, colw = row & 15;
        int kk = kc >> 2, qd = kc & 3;
        int slot = (nt * 4 + kk) * 64 + (colw + 16 * qd);
        uint4 u;
        u.x = pk2(f0.x, f0.y); u.y = pk2(f0.z, f0.w);
        u.z = pk2(f1.x, f1.y); u.w = pk2(f1.z, f1.w);
        *(uint4*)&Wl[slot * 8] = u;
    }

    const int wv = t >> 6, lane = t & 63;
    const int col = lane & 15, quad = lane >> 4;
    const int b = blockIdx.x >> 4;      // batch (fixed per block)
    const int chunk = blockIdx.x & 15;  // 512-row chunk within batch

    float qv[8], bv[8];
#pragma unroll
    for (int nt = 0; nt < 8; nt++) {
        qv[nt] = q[b * DD + nt * 16 + col];
        bv[nt] = b_enc[nt * 16 + col];
    }

    const float4* base = (const float4*)(ctx + ((size_t)b * SS + (size_t)chunk * 512) * DD);

    float4 R[2][8];
    // prologue: tile 0 -> R[0], pack -> Cl
#pragma unroll
    for (int i = 0; i < 8; i++) R[0][i] = base[t + 256 * i];
#pragma unroll
    for (int i = 0; i < 8; i++) {
        int row = (t >> 5) + 8 * i;
        int c = row & 15, w = row >> 4;
        int piece = w * 512 + c * 32 + ((t & 31) ^ (2 * (c & 7)));
        float4 f = R[0][i];
        uint2 pk;
        pk.x = pk2(f.x, f.y); pk.y = pk2(f.z, f.w);
        *(uint2*)&Cl[piece * 4] = pk;
    }
    __syncthreads();  // Wl + Cl(tile0) ready

    float Mrun = -INFINITY, Trun = 0.f;
    float4 acc4 = {0.f, 0.f, 0.f, 0.f};

#pragma unroll
    for (int it = 0; it < 8; ++it) {
        // issue loads for tile it+1 (dense, 1KB/instr)
        if (it < 7) {
            const float4* tb = base + (size_t)(it + 1) * 2048;
#pragma unroll
            for (int i = 0; i < 8; i++) R[(it + 1) & 1][i] = tb[t + 256 * i];
        }

        // ---- MFMA: A = ctx rows (wv*16+col), B = W_enc^T
        bf16x8 a[4];
#pragma unroll
        for (int kk = 0; kk < 4; kk++) {
            int piece = wv * 512 + col * 32 + ((kk * 8 + quad * 2) ^ (2 * (col & 7)));
            a[kk] = *(const bf16x8*)&Cl[piece * 4];
        }
        f32x4 acc[8];
#pragma unroll
        for (int nt = 0; nt < 8; nt++) {
            f32x4 c = {0.f, 0.f, 0.f, 0.f};
#pragma unroll
            for (int kk = 0; kk < 4; kk++) {
                bf16x8 bf = *(const bf16x8*)&Wl[((nt * 4 + kk) * 64 + lane) * 8];
                c = __builtin_amdgcn_mfma_f32_16x16x32_bf16(a[kk], bf, c, 0, 0, 0);
            }
            acc[nt] = c;
        }

        // ---- epilogue: tanh, dot q, reduce over cols; write sw + raw scores
#pragma unroll
        for (int r = 0; r < 4; r++) {
            float v = 0.f;
#pragma unroll
            for (int nt = 0; nt < 8; nt++)
                v += tanh_fast(acc[nt][r] + bv[nt]) * qv[nt];
            v += __shfl_xor(v, 1);
            v += __shfl_xor(v, 2);
            v += __shfl_xor(v, 4);
            v += __shfl_xor(v, 8);
            if (col == 0) {
                int lrow = wv * 16 + quad * 4 + r;
                sw[lrow] = v;
                scores[(size_t)b * SS + chunk * 512 + it * 64 + lrow] = v;
            }
        }
        __syncthreads();  // sw ready; Cl reads done

        // ---- redundant per-wave online softmax over the 64 tile rows
        float sv = sw[lane];
        float m = sv;
#pragma unroll
        for (int off = 1; off < 64; off <<= 1) m = fmaxf(m, __shfl_xor(m, off));
        float Mnew = fmaxf(Mrun, m);
        float alpha = __expf(Mrun - Mnew);
        float wlane = __expf(sv - Mnew);
        float ts = wlane;
#pragma unroll
        for (int off = 1; off < 64; off <<= 1) ts += __shfl_xor(ts, off);
        Trun = Trun * alpha + ts;
        Mrun = Mnew;

        // ---- weighted ctx accumulation from the fp32 register tile
        acc4.x *= alpha; acc4.y *= alpha; acc4.z *= alpha; acc4.w *= alpha;
#pragma unroll
        for (int i = 0; i < 8; i++) {
            int row_i = (t >> 5) + 8 * i;  // row this thread's piece i belongs to
            float wi = __shfl(wlane, row_i);
            float4 Rv = R[it & 1][i];
            acc4.x += wi * Rv.x;
            acc4.y += wi * Rv.y;
            acc4.z += wi * Rv.z;
            acc4.w += wi * Rv.w;
        }

        // ---- pack tile it+1 into Cl
        if (it < 7) {
#pragma unroll
            for (int i = 0; i < 8; i++) {
                int row = (t >> 5) + 8 * i;
                int c = row & 15, w = row >> 4;
                int piece = w * 512 + c * 32 + ((t & 31) ^ (2 * (c & 7)));
                float4 f = R[(it + 1) & 1][i];
                uint2 pk;
                pk.x = pk2(f.x, f.y); pk.y = pk2(f.z, f.w);
                *(uint2*)&Cl[piece * 4] = pk;
            }
        }
        __syncthreads();  // Cl(it+1) ready; sw free for rewrite
    }

    // ---- block-reduce acc4 (thread t holds dims [4*(t&31),+4) over row subset)
    float4* red = (float4*)Cl;
    red[t] = acc4;
    __syncthreads();
    if (t < 32) {
        float4 s = red[t];
#pragma unroll
        for (int k = 1; k < 8; k++) {
            float4 p = red[t + 32 * k];
            s.x += p.x; s.y += p.y; s.z += p.z; s.w += p.w;
        }
        *(float4*)&wcp[(size_t)blockIdx.x * DD + 4 * t] = s;
    }
    if (t == 0) {
        Mp[blockIdx.x] = Mrun;
        Tp[blockIdx.x] = Tp ? Trun : Trun;  // plain store
        Tp[blockIdx.x] = Trun;
    }
}

// ---------------- K3: combine 16 per-block partials per batch -> wc, M, 1/T
__global__ void combine_kernel(const float* __restrict__ wcp,
                               const float* __restrict__ Mp,
                               const float* __restrict__ Tp,
                               float* __restrict__ wc,
                               float* __restrict__ Ms,
                               float* __restrict__ Tinv) {
    const int b = blockIdx.x, d = threadIdx.x;  // 128 threads
    float M = -INFINITY;
#pragma unroll
    for (int j = 0; j < 16; j++) M = fmaxf(M, Mp[b * 16 + j]);
    float T = 0.f, acc = 0.f;
#pragma unroll
    for (int j = 0; j < 16; j++) {
        float e = __expf(Mp[b * 16 + j] - M);
        T += Tp[b * 16 + j] * e;
        acc += wcp[(size_t)(b * 16 + j) * DD + d] * e;
    }
    float ti = 1.f / T;
    wc[b * DD + d] = acc * ti;
    if (d == 0) { Ms[b] = M; Tinv[b] = ti; }
}

// ---------------- K4: attn = exp(scores - M)/T
__global__ __launch_bounds__(512) void attnfin_kernel(const float* __restrict__ scores,
                                                      const float* __restrict__ Ms,
                                                      const float* __restrict__ Tinv,
                                                      float* __restrict__ attn) {
    const int b = blockIdx.x >> 2, seg = blockIdx.x & 3;
    const float M = Ms[b], ti = Tinv[b];
    const float4* s4 = (const float4*)(scores + (size_t)b * SS) + seg * 512;
    float4* a4 = (float4*)(attn + (size_t)b * SS) + seg * 512;
    float4 v = s4[threadIdx.x];
    v.x = __expf(v.x - M) * ti;
    v.y = __expf(v.y - M) * ti;
    v.z = __expf(v.z - M) * ti;
    v.w = __expf(v.w - M) * ti;
    a4[threadIdx.x] = v;
}

// ---------------- K5: h = tanh(concat(wc, q) @ W_out^T)
__global__ void out_kernel(const float* __restrict__ wc,
                           const float* __restrict__ q,
                           const float* __restrict__ W_out,
                           float* __restrict__ h) {
    __shared__ float cat[2 * DD];
    const int b = blockIdx.x, d = threadIdx.x;  // 128 threads
    cat[d] = wc[b * DD + d];
    cat[DD + d] = q[b * DD + d];
    __syncthreads();
    const float4* wrow = (const float4*)(W_out + (size_t)d * 2 * DD);
    float acc = 0.f;
#pragma unroll
    for (int k4 = 0; k4 < 2 * DD / 4; k4++) {
        float4 w = wrow[k4];
        float4 x = ((const float4*)cat)[k4];
        acc += w.x * x.x + w.y * x.y + w.z * x.z + w.w * x.w;
    }
    h[b * DD + d] = tanh_fast(acc);
}

extern "C" void kernel_launch(void* const* d_in, const int* in_sizes, int n_in,
                              void* d_out, int out_size, void* d_ws, size_t ws_size,
                              hipStream_t stream) {
    const float* input = (const float*)d_in[0];
    const float* ctx   = (const float*)d_in[1];
    const float* W_enc = (const float*)d_in[2];
    const float* b_enc = (const float*)d_in[3];
    const float* W_dec = (const float*)d_in[4];
    const float* b_dec = (const float*)d_in[5];
    const float* W_out = (const float*)d_in[6];

    float* h    = (float*)d_out;            // [B, D]
    float* attn = (float*)d_out + BB * DD;  // [B, S]

    float* ws     = (float*)d_ws;
    float* q      = ws;                     // 8192
    float* wc     = ws + 8192;              // 8192
    float* scores = ws + 16384;             // 524288 raw scores
    float* wcp    = ws + 16384 + 524288;    // 1024*128 partials
    float* Mp     = wcp + 1024 * DD;        // 1024
    float* Tp     = Mp + 1024;              // 1024
    float* Ms     = Tp + 1024;              // 64
    float* Tinv   = Ms + 64;                // 64

    qproj_kernel<<<BB, DD, 0, stream>>>(input, W_dec, b_dec, q);
    score_fused_kernel<<<BB * 16, 256, 0, stream>>>(ctx, W_enc, b_enc, q,
                                                    scores, wcp, Mp, Tp);
    combine_kernel<<<BB, DD, 0, stream>>>(wcp, Mp, Tp, wc, Ms, Tinv);
    attnfin_kernel<<<BB * 4, 512, 0, stream>>>(scores, Ms, Tinv, attn);
    out_kernel<<<BB, DD, 0, stream>>>(wc, q, W_out, h);
}

// Round 4
// 420.753 us; speedup vs baseline: 1.2675x; 1.2675x over previous
//
#include <hip/hip_runtime.h>
#include <hip/hip_bf16.h>

#define BB 64
#define SS 8192
#define DD 128

typedef __attribute__((ext_vector_type(8))) short bf16x8;
typedef __attribute__((ext_vector_type(4))) float f32x4;

// swizzled slot within a (w,kk) 128-slot region; 8-byte units
#define SWZ(c, qd) ((qd) * 16 + ((c) ^ (2 * (qd))))

__device__ __forceinline__ unsigned pk2(float x, float y) {
    __hip_bfloat162 h = __float22bfloat162_rn(make_float2(x, y));
    union { __hip_bfloat162 h2; unsigned u; } cv;
    cv.h2 = h;
    return cv.u;
}

__device__ __forceinline__ float bflo(unsigned p) { return __uint_as_float(p << 16); }
__device__ __forceinline__ float bfhi(unsigned p) { return __uint_as_float(p & 0xffff0000u); }

__device__ __forceinline__ float tanh_fast(float x) {
    float e = __expf(2.f * x);
    return 1.f - 2.f / (e + 1.f);
}

// ---------------- K1: q = tanh(input @ W_dec^T + b_dec)
__global__ void qproj_kernel(const float* __restrict__ input,
                             const float* __restrict__ W_dec,
                             const float* __restrict__ b_dec,
                             float* __restrict__ q) {
    __shared__ float xin[DD];
    const int b = blockIdx.x, d = threadIdx.x;  // 128 threads
    xin[d] = input[b * DD + d];
    __syncthreads();
    const float4* wrow = (const float4*)(W_dec + (size_t)d * DD);
    float acc = 0.f;
#pragma unroll
    for (int k4 = 0; k4 < DD / 4; k4++) {
        float4 w = wrow[k4];
        float4 x = ((const float4*)xin)[k4];
        acc += w.x * x.x + w.y * x.y + w.z * x.z + w.w * x.w;
    }
    q[b * DD + d] = tanh_fast(acc + b_dec[d]);
}

// ---------------- K2: fused scores + online softmax + weighted ctx sum
// 64 batches x 16 chunks; 8 tiles of 64 rows per block. Single register
// staging buffer R[8] (no spill), bf16 XOR-swizzled LDS tile feeds BOTH the
// MFMA fragments and the weighted-context accumulation.
__global__ __launch_bounds__(256, 3) void score_fused_kernel(
    const float* __restrict__ ctx,
    const float* __restrict__ W_enc,
    const float* __restrict__ b_enc,
    const float* __restrict__ q,
    float* __restrict__ scores,
    float* __restrict__ wcp,   // [1024][128]
    float* __restrict__ Mp,    // [1024]
    float* __restrict__ Tp) {  // [1024]
    __shared__ __align__(16) short Wl[16384];  // 32 KB fragment-order W_enc
    __shared__ __align__(16) short Cl[8192];   // 16 KB swizzled bf16 ctx tile
    __shared__ float sw[64];
    __shared__ float4 red[256];

    const int t = threadIdx.x;

    // ---- stage W_enc: region (nt*4+kk), slot SWZ(col,qd), halves h=0/1
    const float4* W4 = (const float4*)W_enc;
    for (int c2 = t; c2 < 2048; c2 += 256) {
        int row = c2 >> 4, kc = c2 & 15;
        float4 f0 = W4[row * 32 + kc * 2];
        float4 f1 = W4[row * 32 + kc * 2 + 1];
        int nt = row >> 4, colw = row & 15, kk = kc >> 2, qd = kc & 3;
        int a8 = (nt * 4 + kk) * 128 + SWZ(colw, qd) * 2;
        uint4 u;
        u.x = pk2(f0.x, f0.y); u.y = pk2(f0.z, f0.w);
        u.z = pk2(f1.x, f1.y); u.w = pk2(f1.z, f1.w);
        *(uint4*)&Wl[a8 * 4] = u;
    }

    const int wv = t >> 6, lane = t & 63;
    const int col = lane & 15, quad = lane >> 4;
    const int b = blockIdx.x >> 4;
    const int chunk = blockIdx.x & 15;

    // per-thread piece coords for pack / weighted-sum
    const int u = t & 31, rg = t >> 5;
    const int ukk = u >> 3, uqd = (u >> 1) & 3, uh = u & 1;

    float qv[8], bv[8];
#pragma unroll
    for (int nt = 0; nt < 8; nt++) {
        qv[nt] = q[b * DD + nt * 16 + col];
        bv[nt] = b_enc[nt * 16 + col];
    }

    const float4* base = (const float4*)(ctx + ((size_t)b * SS + (size_t)chunk * 512) * DD);

    float4 R[8];
    // pack R -> Cl at this thread's 8 (row, piece) slots
    auto pack_tile = [&]() {
#pragma unroll
        for (int i = 0; i < 8; i++) {
            int row = rg + 8 * i, w = row >> 4, c = row & 15;
            int a8 = (w * 4 + ukk) * 128 + SWZ(c, uqd) * 2 + uh;
            uint2 pk;
            pk.x = pk2(R[i].x, R[i].y);
            pk.y = pk2(R[i].z, R[i].w);
            *(uint2*)&Cl[a8 * 4] = pk;
        }
    };

    // prologue: tile 0
#pragma unroll
    for (int i = 0; i < 8; i++) R[i] = base[t + 256 * i];
    pack_tile();
    __syncthreads();

    float Mrun = -INFINITY, Trun = 0.f;
    float4 acc4 = {0.f, 0.f, 0.f, 0.f};

    for (int it = 0; it < 8; ++it) {
        // prefetch next tile into the (now free) single register buffer
        if (it < 7) {
            const float4* tb = base + (size_t)(it + 1) * 2048;
#pragma unroll
            for (int i = 0; i < 8; i++) R[i] = tb[t + 256 * i];
        }

        // ---- MFMA from swizzled Cl / Wl
        bf16x8 a[4];
#pragma unroll
        for (int kk = 0; kk < 4; kk++) {
            int a8 = (wv * 4 + kk) * 128 + SWZ(col, quad) * 2;
            a[kk] = *(const bf16x8*)&Cl[a8 * 4];
        }
        f32x4 acc[8];
#pragma unroll
        for (int nt = 0; nt < 8; nt++) {
            f32x4 c = {0.f, 0.f, 0.f, 0.f};
#pragma unroll
            for (int kk = 0; kk < 4; kk++) {
                int a8 = (nt * 4 + kk) * 128 + SWZ(col, quad) * 2;
                bf16x8 bf = *(const bf16x8*)&Wl[a8 * 4];
                c = __builtin_amdgcn_mfma_f32_16x16x32_bf16(a[kk], bf, c, 0, 0, 0);
            }
            acc[nt] = c;
        }

        // ---- epilogue: tanh, dot q, col-reduce, write sw + raw scores
#pragma unroll
        for (int r = 0; r < 4; r++) {
            float v = 0.f;
#pragma unroll
            for (int nt = 0; nt < 8; nt++)
                v += tanh_fast(acc[nt][r] + bv[nt]) * qv[nt];
            v += __shfl_xor(v, 1);
            v += __shfl_xor(v, 2);
            v += __shfl_xor(v, 4);
            v += __shfl_xor(v, 8);
            if (col == 0) {
                int lrow = wv * 16 + quad * 4 + r;
                sw[lrow] = v;
                scores[(size_t)b * SS + chunk * 512 + it * 64 + lrow] = v;
            }
        }
        __syncthreads();  // sw visible; frag reads of Cl done

        // ---- per-wave (redundant) online softmax over this tile's 64 rows
        float sv = sw[lane];
        float m = sv;
#pragma unroll
        for (int off = 1; off < 64; off <<= 1) m = fmaxf(m, __shfl_xor(m, off));
        float Mnew = fmaxf(Mrun, m);
        float alpha = __expf(Mrun - Mnew);
        float wlane = __expf(sv - Mnew);
        float ts = wlane;
#pragma unroll
        for (int off = 1; off < 64; off <<= 1) ts += __shfl_xor(ts, off);
        Trun = Trun * alpha + ts;
        Mrun = Mnew;

        // ---- weighted ctx accumulation from the bf16 LDS tile
        acc4.x *= alpha; acc4.y *= alpha; acc4.z *= alpha; acc4.w *= alpha;
#pragma unroll
        for (int i = 0; i < 8; i++) {
            int row = rg + 8 * i, w = row >> 4, c = row & 15;
            int a8 = (w * 4 + ukk) * 128 + SWZ(c, uqd) * 2 + uh;
            uint2 pk = *(const uint2*)&Cl[a8 * 4];
            float wi = __shfl(wlane, row);
            acc4.x += wi * bflo(pk.x);
            acc4.y += wi * bfhi(pk.x);
            acc4.z += wi * bflo(pk.y);
            acc4.w += wi * bfhi(pk.y);
        }
        __syncthreads();  // all Cl reads done

        if (it < 7) {
            pack_tile();
            __syncthreads();  // Cl(it+1) ready
        }
    }

    // ---- block reduce: thread t holds dims [4u,4u+4) over row-group rg
    red[t] = acc4;
    __syncthreads();
    if (t < 32) {
        float4 s = red[t];
#pragma unroll
        for (int k = 1; k < 8; k++) {
            float4 p = red[t + 32 * k];
            s.x += p.x; s.y += p.y; s.z += p.z; s.w += p.w;
        }
        *(float4*)&wcp[(size_t)blockIdx.x * DD + 4 * t] = s;
    }
    if (t == 0) {
        Mp[blockIdx.x] = Mrun;
        Tp[blockIdx.x] = Trun;
    }
}

// ---------------- K3: combine 16 per-block partials per batch
__global__ void combine_kernel(const float* __restrict__ wcp,
                               const float* __restrict__ Mp,
                               const float* __restrict__ Tp,
                               float* __restrict__ wc,
                               float* __restrict__ Ms,
                               float* __restrict__ Tinv) {
    const int b = blockIdx.x, d = threadIdx.x;  // 128 threads
    float M = -INFINITY;
#pragma unroll
    for (int j = 0; j < 16; j++) M = fmaxf(M, Mp[b * 16 + j]);
    float T = 0.f, acc = 0.f;
#pragma unroll
    for (int j = 0; j < 16; j++) {
        float e = __expf(Mp[b * 16 + j] - M);
        T += Tp[b * 16 + j] * e;
        acc += wcp[(size_t)(b * 16 + j) * DD + d] * e;
    }
    float ti = 1.f / T;
    wc[b * DD + d] = acc * ti;
    if (d == 0) { Ms[b] = M; Tinv[b] = ti; }
}

// ---------------- K4: attn = exp(scores - M)/T
__global__ __launch_bounds__(512) void attnfin_kernel(const float* __restrict__ scores,
                                                      const float* __restrict__ Ms,
                                                      const float* __restrict__ Tinv,
                                                      float* __restrict__ attn) {
    const int b = blockIdx.x >> 2, seg = blockIdx.x & 3;
    const float M = Ms[b], ti = Tinv[b];
    const float4* s4 = (const float4*)(scores + (size_t)b * SS) + seg * 512;
    float4* a4 = (float4*)(attn + (size_t)b * SS) + seg * 512;
    float4 v = s4[threadIdx.x];
    v.x = __expf(v.x - M) * ti;
    v.y = __expf(v.y - M) * ti;
    v.z = __expf(v.z - M) * ti;
    v.w = __expf(v.w - M) * ti;
    a4[threadIdx.x] = v;
}

// ---------------- K5: h = tanh(concat(wc, q) @ W_out^T)
__global__ void out_kernel(const float* __restrict__ wc,
                           const float* __restrict__ q,
                           const float* __restrict__ W_out,
                           float* __restrict__ h) {
    __shared__ float cat[2 * DD];
    const int b = blockIdx.x, d = threadIdx.x;  // 128 threads
    cat[d] = wc[b * DD + d];
    cat[DD + d] = q[b * DD + d];
    __syncthreads();
    const float4* wrow = (const float4*)(W_out + (size_t)d * 2 * DD);
    float acc = 0.f;
#pragma unroll
    for (int k4 = 0; k4 < 2 * DD / 4; k4++) {
        float4 w = wrow[k4];
        float4 x = ((const float4*)cat)[k4];
        acc += w.x * x.x + w.y * x.y + w.z * x.z + w.w * x.w;
    }
    h[b * DD + d] = tanh_fast(acc);
}

extern "C" void kernel_launch(void* const* d_in, const int* in_sizes, int n_in,
                              void* d_out, int out_size, void* d_ws, size_t ws_size,
                              hipStream_t stream) {
    const float* input = (const float*)d_in[0];
    const float* ctx   = (const float*)d_in[1];
    const float* W_enc = (const float*)d_in[2];
    const float* b_enc = (const float*)d_in[3];
    const float* W_dec = (const float*)d_in[4];
    const float* b_dec = (const float*)d_in[5];
    const float* W_out = (const float*)d_in[6];

    float* h    = (float*)d_out;            // [B, D]
    float* attn = (float*)d_out + BB * DD;  // [B, S]

    float* ws     = (float*)d_ws;
    float* q      = ws;                     // 8192
    float* wc     = ws + 8192;              // 8192
    float* scores = ws + 16384;             // 524288 raw scores
    float* wcp    = ws + 16384 + 524288;    // 1024*128 partials
    float* Mp     = wcp + 1024 * DD;        // 1024
    float* Tp     = Mp + 1024;              // 1024
    float* Ms     = Tp + 1024;              // 64
    float* Tinv   = Ms + 64;                // 64

    qproj_kernel<<<BB, DD, 0, stream>>>(input, W_dec, b_dec, q);
    score_fused_kernel<<<BB * 16, 256, 0, stream>>>(ctx, W_enc, b_enc, q,
                                                    scores, wcp, Mp, Tp);
    combine_kernel<<<BB, DD, 0, stream>>>(wcp, Mp, Tp, wc, Ms, Tinv);
    attnfin_kernel<<<BB * 4, 512, 0, stream>>>(scores, Ms, Tinv, attn);
    out_kernel<<<BB, DD, 0, stream>>>(wc, q, W_out, h);
}